// Round 5
// baseline (363.022 us; speedup 1.0000x reference)
//
#include <hip/hip_runtime.h>
#include <hip/hip_fp16.h>

// Deformable RoI pooling (MMCV-style), forward only.
// features: (B=8, C=256, H=168, W=168) fp32 = 231 MB
// rois:     (N=512, 5)  [bidx, x1, y1, x2, y2]
// offset:   (N=512, 2, PH=7, PW=7)
// out:      (N, C, PH, PW) fp32
//
// Round 5: kill the scattered-LDS structure.
//  1) transpose_pairs: NCHW fp32 -> T[b][p][cpair] __half2 in d_ws (115.6 MB).
//  2) build_desc: per-(roi,bin,sub) {packed p00/dx/dy, lx, ly, scale}.
//  3) droi_sample: one 512-thr block per roi; lanes span channel pairs ->
//     every corner read is a coalesced 256 B wave load from L3-resident T;
//     descriptors are wave-uniform -> scalar loads. Output staged in a
//     50 KB LDS [c][bin] tile, dumped as coalesced float4.

#define PH_ 7
#define PW_ 7
#define SPP_ 2
#define SS_ 0.0625f
#define TRANS_STD_ 0.1f
#define B_ 8
#define C_ 256
#define H_ 168
#define W_ 168
#define N_ 512
#define HW_ (H_ * W_)            // 28224 = 441 * 64
#define BINS_ (PH_ * PW_)        // 49
#define NSUB_ (SPP_ * SPP_)      // 4
#define CP_ (C_ / 2)             // 128 channel pairs

// ws layout: T (__half2[B][HW][CP]) | desc (float4[N][NSUB][BINS])
#define T_BYTES_   ((size_t)B_ * HW_ * CP_ * 4)            // 115,605,504
#define DESC_BYTES_ ((size_t)N_ * NSUB_ * BINS_ * 16)      // 1,605,632
#define WS_NEEDED_ (T_BYTES_ + DESC_BYTES_)

// ---------------- kernel 1: NCHW fp32 -> [b][p][cpair] half2 ----------------
// grid (441 pblk, 4 cblk, 8 b), 256 threads. LDS tile 64c x 64p (+1 pad).
__global__ __launch_bounds__(256) void transpose_pairs(
    const float* __restrict__ features, __half2* __restrict__ T)
{
    __shared__ float tile[64][65];
    const int pblk = blockIdx.x;     // pixel block (64 pixels)
    const int cblk = blockIdx.y;     // channel block (64 channels)
    const int b    = blockIdx.z;
    const int tid  = threadIdx.x;

    // load: lanes span 64 consecutive pixels of one channel row (coalesced)
    {
        const int p_l    = tid & 63;
        const int c_base = tid >> 6;            // 0..3
        const size_t gbase =
            ((size_t)(b * C_ + cblk * 64) ) * HW_ + (size_t)pblk * 64 + p_l;
#pragma unroll 4
        for (int j = 0; j < 16; ++j) {
            const int c_l = j * 4 + c_base;
            tile[c_l][p_l] = features[gbase + (size_t)c_l * HW_];
        }
    }
    __syncthreads();

    // store: lanes span 32 consecutive channel-pairs of one pixel (coalesced)
    {
        const int cp_l   = tid & 31;            // 0..31
        const int p_base = tid >> 5;            // 0..7
#pragma unroll 4
        for (int j = 0; j < 8; ++j) {
            const int p_l = j * 8 + p_base;
            const __half2 h = __halves2half2(
                __float2half(tile[2 * cp_l][p_l]),
                __float2half(tile[2 * cp_l + 1][p_l]));
            T[((size_t)b * HW_ + (size_t)pblk * 64 + p_l) * CP_
              + cblk * 32 + cp_l] = h;
        }
    }
}

// ---------------- kernel 2: sample descriptors ----------------
// one block per roi; lanes 0..48 = bins; each lane does 4 subsamples.
__global__ __launch_bounds__(64) void build_desc(
    const float* __restrict__ rois,
    const float* __restrict__ offset,
    float4* __restrict__ desc)              // [N][NSUB][BINS]
{
    const int r   = blockIdx.x;
    const int bin = threadIdx.x;
    if (bin >= BINS_) return;
    const int ph = bin / PW_;
    const int pw = bin - ph * PW_;

    const float x1r = rois[r * 5 + 1];
    const float y1r = rois[r * 5 + 2];
    const float x2r = rois[r * 5 + 3];
    const float y2r = rois[r * 5 + 4];

    const float sw    = x1r * SS_ - 0.5f;
    const float sh    = y1r * SS_ - 0.5f;
    const float rw    = fmaxf((x2r + 1.0f) * SS_ - 0.5f - sw, 0.1f);
    const float rh    = fmaxf((y2r + 1.0f) * SS_ - 0.5f - sh, 0.1f);
    const float bin_w = rw * (1.0f / PW_);
    const float bin_h = rh * (1.0f / PH_);
    const float sub_w = bin_w * (1.0f / SPP_);
    const float sub_h = bin_h * (1.0f / SPP_);

    const float offx = offset[((r * 2 + 0) * PH_ + ph) * PW_ + pw] * TRANS_STD_;
    const float offy = offset[((r * 2 + 1) * PH_ + ph) * PW_ + pw] * TRANS_STD_;

    const float bx = sw + (float)pw * bin_w + offx * rw;
    const float by = sh + (float)ph * bin_h + offy * rh;

    unsigned pack[NSUB_];
    float lxs[NSUB_], lys[NSUB_];
    int   vals[NSUB_];
    int   cnt = 0;
#pragma unroll
    for (int s = 0; s < NSUB_; ++s) {
        const int ihs = s >> 1;
        const int iws = s & 1;
        const float x = bx + ((float)iws + 0.5f) * sub_w;
        const float y = by + ((float)ihs + 0.5f) * sub_h;
        const int valid = (x > -0.5f) && (x < (float)W_ - 0.5f) &&
                          (y > -0.5f) && (y < (float)H_ - 0.5f);
        const float xc = fminf(fmaxf(x, 0.0f), (float)(W_ - 1));
        const float yc = fminf(fmaxf(y, 0.0f), (float)(H_ - 1));
        const float x0f = floorf(xc);
        const float y0f = floorf(yc);
        const int x0 = (int)x0f;
        const int y0 = (int)y0f;
        const int dx = (x0 + 1 <= W_ - 1) ? 1 : 0;
        const int dy = (y0 + 1 <= H_ - 1) ? 1 : 0;
        pack[s] = (unsigned)(y0 * W_ + x0) | ((unsigned)dx << 15) |
                  ((unsigned)dy << 16);
        lxs[s] = xc - x0f;
        lys[s] = yc - y0f;
        vals[s] = valid;
        cnt += valid;
    }
    const float inv = (cnt > 0) ? (1.0f / (float)cnt) : 0.0f;
#pragma unroll
    for (int s = 0; s < NSUB_; ++s) {
        float4 d;
        d.x = __uint_as_float(pack[s]);
        d.y = lxs[s];
        d.z = lys[s];
        d.w = vals[s] ? inv : 0.0f;
        desc[((size_t)r * NSUB_ + s) * BINS_ + bin] = d;
    }
}

// ---------------- kernel 3: gather from T ----------------
// one 512-thread block per roi. tid -> (bin-group 0..3, channel-pair 0..127).
__global__ __launch_bounds__(512) void droi_sample(
    const __half2* __restrict__ T,
    const float* __restrict__ rois,
    const float4* __restrict__ desc,
    float* __restrict__ out)
{
    __shared__ float tile[C_ * BINS_];      // [c][bin], 50,176 B

    const int r   = blockIdx.x;
    const int tid = threadIdx.x;
    const int bg  = tid >> 7;               // 0..3  (wave-uniform)
    const int cp  = tid & 127;              // channel pair
    const int b   = (int)rois[r * 5];       // uniform -> scalar

    const __half2* __restrict__ Tb = T + (size_t)b * HW_ * CP_ + cp;

    for (int bin = bg; bin < BINS_; bin += 4) {
        const int bin_u = __builtin_amdgcn_readfirstlane(bin);
        float acc0 = 0.0f, acc1 = 0.0f;
#pragma unroll
        for (int s = 0; s < NSUB_; ++s) {
            const float4 d = desc[((size_t)r * NSUB_ + s) * BINS_ + bin_u];
            const unsigned pk = __float_as_uint(d.x);
            const int p00 = (int)(pk & 0x7FFFu);
            const int dx  = (int)((pk >> 15) & 1u);
            const int dyW = (int)((pk >> 16) & 1u) * W_;
            const float lx = d.y, ly = d.z, sc = d.w;

            const __half2 h00 = Tb[(size_t)p00 * CP_];
            const __half2 h01 = Tb[(size_t)(p00 + dx) * CP_];
            const __half2 h10 = Tb[(size_t)(p00 + dyW) * CP_];
            const __half2 h11 = Tb[(size_t)(p00 + dyW + dx) * CP_];

            const float f00x = __low2float(h00), f00y = __high2float(h00);
            const float f01x = __low2float(h01), f01y = __high2float(h01);
            const float f10x = __low2float(h10), f10y = __high2float(h10);
            const float f11x = __low2float(h11), f11y = __high2float(h11);

            const float tx = f00x + lx * (f01x - f00x);
            const float bxv = f10x + lx * (f11x - f10x);
            acc0 += sc * (tx + ly * (bxv - tx));

            const float ty = f00y + lx * (f01y - f00y);
            const float byv = f10y + lx * (f11y - f10y);
            acc1 += sc * (ty + ly * (byv - ty));
        }
        tile[(2 * cp) * BINS_ + bin_u]     = acc0;
        tile[(2 * cp + 1) * BINS_ + bin_u] = acc1;
    }
    __syncthreads();

    // coalesced float4 dump: tile is exactly out[r]'s [c][bin] layout
    const float4* __restrict__ t4 = reinterpret_cast<const float4*>(tile);
    float4* __restrict__ o4 =
        reinterpret_cast<float4*>(out + (size_t)r * (C_ * BINS_));
    for (int k = tid; k < (C_ * BINS_) / 4; k += 512) o4[k] = t4[k];
}

// ---------------- fallback (round-1 kernel) if ws too small ----------------
__global__ __launch_bounds__(64) void droi_pool_fallback(
    const float* __restrict__ features,
    const float* __restrict__ rois,
    const float* __restrict__ offset,
    float* __restrict__ out)
{
    const int blk  = blockIdx.x;
    const int n    = blk >> 8;
    const int c    = blk & 255;
    const int lane = threadIdx.x;
    if (lane >= BINS_) return;
    const int ph = lane / PW_;
    const int pw = lane % PW_;

    const float r0  = rois[n * 5 + 0];
    const float x1r = rois[n * 5 + 1];
    const float y1r = rois[n * 5 + 2];
    const float x2r = rois[n * 5 + 3];
    const float y2r = rois[n * 5 + 4];
    const int   b   = (int)r0;

    const float sw    = x1r * SS_ - 0.5f;
    const float sh    = y1r * SS_ - 0.5f;
    const float rw    = fmaxf((x2r + 1.0f) * SS_ - 0.5f - sw, 0.1f);
    const float rh    = fmaxf((y2r + 1.0f) * SS_ - 0.5f - sh, 0.1f);
    const float bin_w = rw / PW_;
    const float bin_h = rh / PH_;
    const float sub_w = bin_w / SPP_;
    const float sub_h = bin_h / SPP_;

    const float offx = offset[((n * 2 + 0) * PH_ + ph) * PW_ + pw] * TRANS_STD_;
    const float offy = offset[((n * 2 + 1) * PH_ + ph) * PW_ + pw] * TRANS_STD_;

    const float bx = sw + (float)pw * bin_w + offx * rw;
    const float by = sh + (float)ph * bin_h + offy * rh;

    const float* __restrict__ f =
        features + (size_t)(b * C_ + c) * (size_t)HW_;

    float s = 0.0f;
    int cnt = 0;
#pragma unroll
    for (int ihs = 0; ihs < SPP_; ++ihs) {
#pragma unroll
        for (int iws = 0; iws < SPP_; ++iws) {
            const float x = bx + ((float)iws + 0.5f) * sub_w;
            const float y = by + ((float)ihs + 0.5f) * sub_h;
            const bool valid = (x > -0.5f) && (x < (float)W_ - 0.5f) &&
                               (y > -0.5f) && (y < (float)H_ - 0.5f);
            const float xc = fminf(fmaxf(x, 0.0f), (float)(W_ - 1));
            const float yc = fminf(fmaxf(y, 0.0f), (float)(H_ - 1));
            const float x0f = floorf(xc);
            const float y0f = floorf(yc);
            const float lx = xc - x0f;
            const float ly = yc - y0f;
            const int x0 = (int)x0f;
            const int y0 = (int)y0f;
            const int x1i = min(x0 + 1, W_ - 1);
            const int y1i = min(y0 + 1, H_ - 1);
            const float f00 = f[y0  * W_ + x0 ];
            const float f01 = f[y0  * W_ + x1i];
            const float f10 = f[y1i * W_ + x0 ];
            const float f11 = f[y1i * W_ + x1i];
            const float v = (1.0f - ly) * (1.0f - lx) * f00 +
                            (1.0f - ly) * lx          * f01 +
                            ly          * (1.0f - lx) * f10 +
                            ly          * lx          * f11;
            if (valid) { s += v; cnt += 1; }
        }
    }
    const float res = (cnt > 0) ? (s / (float)cnt) : 0.0f;
    out[(size_t)(n * C_ + c) * BINS_ + lane] = res;
}

extern "C" void kernel_launch(void* const* d_in, const int* in_sizes, int n_in,
                              void* d_out, int out_size, void* d_ws, size_t ws_size,
                              hipStream_t stream) {
    const float* features = (const float*)d_in[0];
    const float* rois     = (const float*)d_in[1];
    const float* offset   = (const float*)d_in[2];
    float*       out      = (float*)d_out;

    if (ws_size >= WS_NEEDED_) {
        __half2* T   = reinterpret_cast<__half2*>(d_ws);
        float4* desc = reinterpret_cast<float4*>((char*)d_ws + T_BYTES_);
        hipLaunchKernelGGL(transpose_pairs, dim3(HW_ / 64, C_ / 64, B_),
                           dim3(256), 0, stream, features, T);
        hipLaunchKernelGGL(build_desc, dim3(N_), dim3(64), 0, stream,
                           rois, offset, desc);
        hipLaunchKernelGGL(droi_sample, dim3(N_), dim3(512), 0, stream,
                           T, rois, desc, out);
    } else {
        hipLaunchKernelGGL(droi_pool_fallback, dim3(N_ * C_), dim3(64), 0, stream,
                           features, rois, offset, out);
    }
}